// Round 2
// baseline (276.964 us; speedup 1.0000x reference)
//
#include <hip/hip_runtime.h>

// Cosine-similarity attention context:
//   dots[s]  = keys[s,:] . q
//   cos[s]   = dots[s] / (||q|| * ||keys[s,:]||)
//   ctx[h]   = sum_s cos[s] * keys[s,h]
// keys = 32768 x 1024 f32 (128 MiB) -> single HBM pass, BW-bound (~20 us floor).
//
// R1 -> R2: harness poison(512MiB ws)+restore dominate dur_us; our controllable
// slice is the graph itself. Collapse to 2 nodes: memset(out,4KiB) + one kernel
// (per-block reduce -> device-scope atomicAdd). Drops the reduce kernel + ws
// round-trip. 1024 blocks for deeper latency hiding.

constexpr int H   = 1024;   // hidden dim (fixed by problem)
constexpr int TPB = 256;    // 4 waves per block
constexpr int WPB = TPB / 64;
constexpr int NBLOCKS = 1024;   // 4 blocks/CU target, 8 rows/wave at S=32768

__global__ __launch_bounds__(TPB, 4)
void cosctx_fused(const float* __restrict__ q,
                  const float* __restrict__ keys,
                  int S,
                  float* __restrict__ out)
{
    const int lane  = threadIdx.x & 63;
    const int wave  = threadIdx.x >> 6;
    const int gwave = blockIdx.x * WPB + wave;
    const int nwaves = gridDim.x * WPB;

    const float4* q4 = reinterpret_cast<const float4*>(q);
    const float4* k4 = reinterpret_cast<const float4*>(keys);

    // --- query fragment + 1/||q|| (redundant per wave; q is 4 KiB, L2-hot) ---
    float4 qv[4];
#pragma unroll
    for (int j = 0; j < 4; ++j) qv[j] = q4[j * 64 + lane];

    float qsq = 0.f;
#pragma unroll
    for (int j = 0; j < 4; ++j)
        qsq += qv[j].x * qv[j].x + qv[j].y * qv[j].y +
               qv[j].z * qv[j].z + qv[j].w * qv[j].w;
#pragma unroll
    for (int off = 32; off > 0; off >>= 1) qsq += __shfl_down(qsq, off, 64);
    const float inv_qn = rsqrtf(__shfl(qsq, 0, 64));

    float4 acc[4];
#pragma unroll
    for (int j = 0; j < 4; ++j) acc[j] = make_float4(0.f, 0.f, 0.f, 0.f);

    // --- single pass over rows, 1-row prefetch pipeline ---
    int row = gwave;
    float4 kv[4];
    if (row < S) {
        const float4* kr = k4 + (size_t)row * (H / 4);
#pragma unroll
        for (int j = 0; j < 4; ++j) kv[j] = kr[j * 64 + lane];
    }
    while (row < S) {
        const int nrow = row + nwaves;
        float4 kn[4];
        if (nrow < S) {
            const float4* kr = k4 + (size_t)nrow * (H / 4);
#pragma unroll
            for (int j = 0; j < 4; ++j) kn[j] = kr[j * 64 + lane];
        }

        float dot = 0.f, ksq = 0.f;
#pragma unroll
        for (int j = 0; j < 4; ++j) {
            dot += kv[j].x * qv[j].x + kv[j].y * qv[j].y +
                   kv[j].z * qv[j].z + kv[j].w * qv[j].w;
            ksq += kv[j].x * kv[j].x + kv[j].y * kv[j].y +
                   kv[j].z * kv[j].z + kv[j].w * kv[j].w;
        }
        // two interleaved (independent) shuffle-reduce chains, no barriers
#pragma unroll
        for (int off = 32; off > 0; off >>= 1) {
            dot += __shfl_down(dot, off, 64);
            ksq += __shfl_down(ksq, off, 64);
        }
        const float score = __shfl(dot, 0, 64) * inv_qn *
                            rsqrtf(__shfl(ksq, 0, 64));

#pragma unroll
        for (int j = 0; j < 4; ++j) {
            acc[j].x += score * kv[j].x;
            acc[j].y += score * kv[j].y;
            acc[j].z += score * kv[j].z;
            acc[j].w += score * kv[j].w;
        }
#pragma unroll
        for (int j = 0; j < 4; ++j) kv[j] = kn[j];
        row = nrow;
    }

    // --- block reduce: 4 wave-partials -> 1 block-partial [H] ---
    __shared__ float sacc[WPB][H];   // 16 KiB
    float4* sa4 = reinterpret_cast<float4*>(sacc[wave]);
#pragma unroll
    for (int j = 0; j < 4; ++j) sa4[j * 64 + lane] = acc[j];
    __syncthreads();

    float4 v = make_float4(0.f, 0.f, 0.f, 0.f);
#pragma unroll
    for (int w = 0; w < WPB; ++w) {
        float4 u = reinterpret_cast<const float4*>(sacc[w])[threadIdx.x];
        v.x += u.x; v.y += u.y; v.z += u.z; v.w += u.w;
    }

    // device-scope atomics straight into out (out pre-zeroed by memset node)
    const int c = threadIdx.x * 4;
    atomicAdd(out + c + 0, v.x);
    atomicAdd(out + c + 1, v.y);
    atomicAdd(out + c + 2, v.z);
    atomicAdd(out + c + 3, v.w);
}

extern "C" void kernel_launch(void* const* d_in, const int* in_sizes, int n_in,
                              void* d_out, int out_size, void* d_ws, size_t ws_size,
                              hipStream_t stream)
{
    const float* q    = (const float*)d_in[0];
    const float* keys = (const float*)d_in[1];
    float* out        = (float*)d_out;
    const int S = in_sizes[1] / H;

    // d_out is poisoned 0xAA before every call; atomics accumulate into it.
    hipMemsetAsync(out, 0, H * sizeof(float), stream);
    cosctx_fused<<<NBLOCKS, TPB, 0, stream>>>(q, keys, S, out);
}

// Round 3
// 195.960 us; speedup vs baseline: 1.4134x; 1.4134x over previous
//
#include <hip/hip_runtime.h>

// Cosine-similarity attention context:
//   dots[s]  = keys[s,:] . q
//   cos[s]   = dots[s] / (||q|| * ||keys[s,:]||)
//   ctx[h]   = sum_s cos[s] * keys[s,h]
// keys = 32768 x 1024 f32 (128 MiB) -> single streaming pass, BW-bound.
//
// R2 post-mortem: 1M contended device-scope atomicAdds (1024/address) cost
// ~110 us -- cross-XCD atomics execute at the coherent (fabric) point, not L2
// (WRITE_SIZE showed 16 MiB for a 4 KiB logical output). R3: zero atomics.
// Main kernel writes 512 block-partials [512][1024] to ws (plain stores);
// reduce kernel sums them with plain stores to out. No memset node needed.

constexpr int H   = 1024;   // hidden dim (fixed by problem)
constexpr int TPB = 256;    // 4 waves per block
constexpr int WPB = TPB / 64;
constexpr int NBLOCKS = 512;    // 2 blocks/CU, proven-fast streaming config (R1)

__global__ __launch_bounds__(TPB, 2)
void cosctx_main(const float* __restrict__ q,
                 const float* __restrict__ keys,
                 int S,
                 float* __restrict__ ws)
{
    const int lane  = threadIdx.x & 63;
    const int wave  = threadIdx.x >> 6;
    const int gwave = blockIdx.x * WPB + wave;
    const int nwaves = gridDim.x * WPB;

    const float4* q4 = reinterpret_cast<const float4*>(q);
    const float4* k4 = reinterpret_cast<const float4*>(keys);

    // --- query fragment + 1/||q|| (redundant per wave; q is 4 KiB, L2-hot) ---
    float4 qv[4];
#pragma unroll
    for (int j = 0; j < 4; ++j) qv[j] = q4[j * 64 + lane];

    float qsq = 0.f;
#pragma unroll
    for (int j = 0; j < 4; ++j)
        qsq += qv[j].x * qv[j].x + qv[j].y * qv[j].y +
               qv[j].z * qv[j].z + qv[j].w * qv[j].w;
#pragma unroll
    for (int off = 32; off > 0; off >>= 1) qsq += __shfl_down(qsq, off, 64);
    const float inv_qn = rsqrtf(__shfl(qsq, 0, 64));

    float4 acc[4];
#pragma unroll
    for (int j = 0; j < 4; ++j) acc[j] = make_float4(0.f, 0.f, 0.f, 0.f);

    // --- single pass over rows, 1-row prefetch pipeline ---
    int row = gwave;
    float4 kv[4];
    if (row < S) {
        const float4* kr = k4 + (size_t)row * (H / 4);
#pragma unroll
        for (int j = 0; j < 4; ++j) kv[j] = kr[j * 64 + lane];
    }
    while (row < S) {
        const int nrow = row + nwaves;
        float4 kn[4];
        if (nrow < S) {
            const float4* kr = k4 + (size_t)nrow * (H / 4);
#pragma unroll
            for (int j = 0; j < 4; ++j) kn[j] = kr[j * 64 + lane];
        }

        float dot = 0.f, ksq = 0.f;
#pragma unroll
        for (int j = 0; j < 4; ++j) {
            dot += kv[j].x * qv[j].x + kv[j].y * qv[j].y +
                   kv[j].z * qv[j].z + kv[j].w * qv[j].w;
            ksq += kv[j].x * kv[j].x + kv[j].y * kv[j].y +
                   kv[j].z * kv[j].z + kv[j].w * kv[j].w;
        }
        // two interleaved (independent) shuffle-reduce chains, no barriers
#pragma unroll
        for (int off = 32; off > 0; off >>= 1) {
            dot += __shfl_down(dot, off, 64);
            ksq += __shfl_down(ksq, off, 64);
        }
        const float score = __shfl(dot, 0, 64) * inv_qn *
                            rsqrtf(__shfl(ksq, 0, 64));

#pragma unroll
        for (int j = 0; j < 4; ++j) {
            acc[j].x += score * kv[j].x;
            acc[j].y += score * kv[j].y;
            acc[j].z += score * kv[j].z;
            acc[j].w += score * kv[j].w;
        }
#pragma unroll
        for (int j = 0; j < 4; ++j) kv[j] = kn[j];
        row = nrow;
    }

    // --- block reduce: 4 wave-partials -> 1 block-partial [H] ---
    __shared__ float sacc[WPB][H];   // 16 KiB
    float4* sa4 = reinterpret_cast<float4*>(sacc[wave]);
#pragma unroll
    for (int j = 0; j < 4; ++j) sa4[j * 64 + lane] = acc[j];
    __syncthreads();

    float4 v = make_float4(0.f, 0.f, 0.f, 0.f);
#pragma unroll
    for (int w = 0; w < WPB; ++w) {
        float4 u = reinterpret_cast<const float4*>(sacc[w])[threadIdx.x];
        v.x += u.x; v.y += u.y; v.z += u.z; v.w += u.w;
    }

    // block-partial to workspace, plain store (no atomics anywhere)
    reinterpret_cast<float4*>(ws)[(size_t)blockIdx.x * (H / 4) + threadIdx.x] = v;
}

// Sum NBLOCKS x H block-partials (2 MiB, L2-resident) -> out. Atomic-free.
// 16 blocks; block b owns 64 columns. 4 waves each sum 128 partial-rows,
// then LDS-combine, first 64 threads store.
__global__ __launch_bounds__(TPB)
void cosctx_reduce(const float* __restrict__ ws, float* __restrict__ out)
{
    const int col   = blockIdx.x * 64 + (threadIdx.x & 63);
    const int chunk = threadIdx.x >> 6;               // 0..3
    const int r0 = chunk * (NBLOCKS / WPB);           // 128 rows per chunk

    float s = 0.f;
#pragma unroll 8
    for (int r = r0; r < r0 + NBLOCKS / WPB; ++r)
        s += ws[(size_t)r * H + col];

    __shared__ float red[WPB][64];
    red[chunk][threadIdx.x & 63] = s;
    __syncthreads();

    if (threadIdx.x < 64) {
        float t = red[0][threadIdx.x] + red[1][threadIdx.x] +
                  red[2][threadIdx.x] + red[3][threadIdx.x];
        out[blockIdx.x * 64 + threadIdx.x] = t;
    }
}

extern "C" void kernel_launch(void* const* d_in, const int* in_sizes, int n_in,
                              void* d_out, int out_size, void* d_ws, size_t ws_size,
                              hipStream_t stream)
{
    const float* q    = (const float*)d_in[0];
    const float* keys = (const float*)d_in[1];
    float* out        = (float*)d_out;
    const int S = in_sizes[1] / H;

    const size_t ws_need = (size_t)NBLOCKS * H * sizeof(float);
    if (ws_size >= ws_need) {
        // 2-node graph, zero atomics: main -> reduce (reduce fully writes out)
        cosctx_main<<<NBLOCKS, TPB, 0, stream>>>(q, keys, S, (float*)d_ws);
        cosctx_reduce<<<H / 64, TPB, 0, stream>>>((const float*)d_ws, out);
    } else {
        // fallback: should not trigger (ws is large); reuse main into out via
        // a tiny ws carved from out is impossible -- emulate with single block
        // accumulation: run main with NBLOCKS partials stored into first part
        // of ws if any, else degrade to one-block-per-column direct compute.
        // Practical harness always provides ws >= 2 MiB; keep main+reduce path.
        cosctx_main<<<NBLOCKS, TPB, 0, stream>>>(q, keys, S, (float*)d_ws);
        cosctx_reduce<<<H / 64, TPB, 0, stream>>>((const float*)d_ws, out);
    }
}